// Round 5
// baseline (920.417 us; speedup 1.0000x reference)
//
#include <hip/hip_runtime.h>

// ---------------------------------------------------------------------------
// NeuralSplineCouplingLayer fused kernel (MI355X / gfx950) — round 5
// Round 4: 713us, MfmaUtil 25%, SQ_LDS_BANK_CONFLICT 6.3e7. Diagnosis: LDS
// A-reads dominate (row-strided reads = 8-way bank conflict, ~250K cyc/CU
// ~= wall). Fixes:
//   1) A stored FRAGMENT-LINEAR in LDS (per-lane contiguous 16B b128 reads,
//      conflict-free — same layout as B)
//   2) ks-outer loop, register-cached A frags reused across the wave's 2
//      N-tiles (4 LDS reads feed 12 MFMAs)
// ---------------------------------------------------------------------------

typedef _Float16 v8h __attribute__((ext_vector_type(8)));
typedef float v4f __attribute__((ext_vector_type(4)));

#define ROWS_PER_BLOCK 32
#define NBLOCKS 2048
#define NWAVES 16

// LDS layout (bytes). All A-planes fragment-linear: plane[mt][ks][lane][8].
//   sInpHi [0,      8192)   2 x 4  x 64 x 8 fp16
//   sInpLo [8192,  16384)
//   sH1Hi  [16384, 49152)   2 x 16 x 64 x 8 fp16
//   sH1Lo  [49152, 81920)
//   sH2Hi  [81920, 114688)
//   sH2Lo  [114688,147456)
//   sRaw   [0,     49664)   32 x 388 f32 — overlays inp+h1 (dead in phase 3)
#define SMEM_BYTES 147456
#define S_INPLO 8192
#define S_H1HI  16384
#define S_H1LO  49152
#define S_H2HI  81920
#define S_H2LO  114688
#define RAW_STRIDE 388

#define LO_SCALE 2048.f
#define LO_INV   (1.f / 2048.f)

__device__ __forceinline__ void split2(float x, _Float16& hi, _Float16& lo) {
    _Float16 h = (_Float16)x;
    hi = h;
    lo = (_Float16)((x - (float)h) * LO_SCALE);
}
__device__ __forceinline__ float silu_f(float v) {
    return v / (1.f + __expf(-v));
}
__device__ __forceinline__ float softplus_f(float v) {
    return v > 15.f ? v : __logf(1.f + __expf(v));
}

// --- prep: W (K x N) f32 -> fragment-contiguous fp16 hi/lo -----------------
// Bfrag[j][ks][lane][e]: col n = j*16+(lane&15), k = ks*32+((lane>>4)<<3)+e.
__global__ void nscl_prep_frag(const float* __restrict__ src,
                               _Float16* __restrict__ hi, _Float16* __restrict__ lo,
                               int K, int N) {
    int idx = blockIdx.x * blockDim.x + threadIdx.x;
    if (idx >= N * K) return;
    const int e    = idx & 7;
    const int lane = (idx >> 3) & 63;
    const int rem  = idx >> 9;
    const int KS   = K >> 5;
    const int ks   = rem % KS;
    const int j    = rem / KS;
    const int n = j * 16 + (lane & 15);
    const int k = ks * 32 + ((lane >> 4) << 3) + e;
    split2(src[k * N + n], hi[idx], lo[idx]);
}

// --- GEMM1/2: sOut(frag,KSout=16) = silu(sA @ W + b). Wave owns 2 N-tiles --
template<int KS>
__device__ __forceinline__ void gemm12(const _Float16* __restrict__ sAhi,
                                       const _Float16* __restrict__ sAlo,
                                       const _Float16* __restrict__ Bhi,
                                       const _Float16* __restrict__ Blo,
                                       const float* __restrict__ bias,
                                       _Float16* __restrict__ sOutHi,
                                       _Float16* __restrict__ sOutLo,
                                       int wave, int lane) {
    const int j0 = wave * 2;
    v4f m0[2] = {{0,0,0,0},{0,0,0,0}};
    v4f m1[2] = {{0,0,0,0},{0,0,0,0}};
    v4f c0[2] = {{0,0,0,0},{0,0,0,0}};
    v4f c1[2] = {{0,0,0,0},{0,0,0,0}};
    #pragma unroll
    for (int ks = 0; ks < KS; ++ks) {
        const int abase = (ks * 64 + lane) * 8;
        v8h a0h = *(const v8h*)(sAhi + abase);
        v8h a0l = *(const v8h*)(sAlo + abase);
        v8h a1h = *(const v8h*)(sAhi + KS * 512 + abase);
        v8h a1l = *(const v8h*)(sAlo + KS * 512 + abase);
        #pragma unroll
        for (int i = 0; i < 2; ++i) {
            const int bo = (((j0 + i) * KS + ks) * 64 + lane) * 8;
            v8h bh = *(const v8h*)(Bhi + bo);
            v8h bl = *(const v8h*)(Blo + bo);
            m0[i] = __builtin_amdgcn_mfma_f32_16x16x32_f16(a0h, bh, m0[i], 0, 0, 0);
            m1[i] = __builtin_amdgcn_mfma_f32_16x16x32_f16(a1h, bh, m1[i], 0, 0, 0);
            c0[i] = __builtin_amdgcn_mfma_f32_16x16x32_f16(a0h, bl, c0[i], 0, 0, 0);
            c0[i] = __builtin_amdgcn_mfma_f32_16x16x32_f16(a0l, bh, c0[i], 0, 0, 0);
            c1[i] = __builtin_amdgcn_mfma_f32_16x16x32_f16(a1h, bl, c1[i], 0, 0, 0);
            c1[i] = __builtin_amdgcn_mfma_f32_16x16x32_f16(a1l, bh, c1[i], 0, 0, 0);
        }
    }
    // epilogue -> fragment layout (out K = 512, 16 ks)
    const int r2b = (lane >> 4) * 4;
    #pragma unroll
    for (int i = 0; i < 2; ++i) {
        const int C  = (j0 + i) * 16 + (lane & 15);
        const int ks2 = C >> 5, g2 = (C >> 3) & 3, e2 = C & 7;
        const float bv = bias[C];
        #pragma unroll
        for (int mt = 0; mt < 2; ++mt) {
            const v4f mm = mt ? m1[i] : m0[i];
            const v4f cc = mt ? c1[i] : c0[i];
            #pragma unroll
            for (int rr = 0; rr < 4; ++rr) {
                float v = silu_f(mm[rr] + cc[rr] * LO_INV + bv);
                const int off = ((mt * 16 + ks2) * 64 + g2 * 16 + r2b + rr) * 8 + e2;
                split2(v, sOutHi[off], sOutLo[off]);
            }
        }
    }
}

// --- GEMM3 chunk: 24 tiles from t0; waves 0..11 own 2 tiles; fp32 out ------
__device__ __forceinline__ void gemm3(const _Float16* __restrict__ sAhi,
                                      const _Float16* __restrict__ sAlo,
                                      const _Float16* __restrict__ Bhi,
                                      const _Float16* __restrict__ Blo,
                                      const float* __restrict__ b3,
                                      float* __restrict__ sRaw,
                                      int t0, int wave, int lane) {
    if (wave >= 12) return;
    const int j0 = t0 + wave * 2;
    v4f m0[2] = {{0,0,0,0},{0,0,0,0}};
    v4f m1[2] = {{0,0,0,0},{0,0,0,0}};
    v4f c0[2] = {{0,0,0,0},{0,0,0,0}};
    v4f c1[2] = {{0,0,0,0},{0,0,0,0}};
    #pragma unroll
    for (int ks = 0; ks < 16; ++ks) {
        const int abase = (ks * 64 + lane) * 8;
        v8h a0h = *(const v8h*)(sAhi + abase);
        v8h a0l = *(const v8h*)(sAlo + abase);
        v8h a1h = *(const v8h*)(sAhi + 8192 + abase);
        v8h a1l = *(const v8h*)(sAlo + 8192 + abase);
        #pragma unroll
        for (int i = 0; i < 2; ++i) {
            const int bo = (((j0 + i) * 16 + ks) * 64 + lane) * 8;
            v8h bh = *(const v8h*)(Bhi + bo);
            v8h bl = *(const v8h*)(Blo + bo);
            m0[i] = __builtin_amdgcn_mfma_f32_16x16x32_f16(a0h, bh, m0[i], 0, 0, 0);
            m1[i] = __builtin_amdgcn_mfma_f32_16x16x32_f16(a1h, bh, m1[i], 0, 0, 0);
            c0[i] = __builtin_amdgcn_mfma_f32_16x16x32_f16(a0h, bl, c0[i], 0, 0, 0);
            c0[i] = __builtin_amdgcn_mfma_f32_16x16x32_f16(a0l, bh, c0[i], 0, 0, 0);
            c1[i] = __builtin_amdgcn_mfma_f32_16x16x32_f16(a1h, bl, c1[i], 0, 0, 0);
            c1[i] = __builtin_amdgcn_mfma_f32_16x16x32_f16(a1l, bh, c1[i], 0, 0, 0);
        }
    }
    const int r2b = (lane >> 4) * 4;
    #pragma unroll
    for (int i = 0; i < 2; ++i) {
        const int C    = (j0 + i) * 16 + (lane & 15);
        const int lcol = (j0 + i - t0) * 16 + (lane & 15);
        const float bv = b3[C];
        #pragma unroll
        for (int mt = 0; mt < 2; ++mt) {
            const v4f mm = mt ? m1[i] : m0[i];
            const v4f cc = mt ? c1[i] : c0[i];
            #pragma unroll
            for (int rr = 0; rr < 4; ++rr) {
                const int R = mt * 16 + r2b + rr;
                sRaw[R * RAW_STRIDE + lcol] = mm[rr] + cc[rr] * LO_INV + bv;
            }
        }
    }
}

__global__ __launch_bounds__(1024, 4)
void nscl_fused(const float* __restrict__ xp, const float* __restrict__ ctxp,
                const float* __restrict__ b1, const float* __restrict__ b2,
                const float* __restrict__ b3,
                const _Float16* __restrict__ W1Thi, const _Float16* __restrict__ W1Tlo,
                const _Float16* __restrict__ W2Thi, const _Float16* __restrict__ W2Tlo,
                const _Float16* __restrict__ W3Thi, const _Float16* __restrict__ W3Tlo,
                float* __restrict__ outY, float* __restrict__ outLD) {
    __shared__ __align__(16) char smem[SMEM_BYTES];
    _Float16* sInpHi = (_Float16*)smem;
    _Float16* sInpLo = (_Float16*)(smem + S_INPLO);
    _Float16* sH1Hi  = (_Float16*)(smem + S_H1HI);
    _Float16* sH1Lo  = (_Float16*)(smem + S_H1LO);
    _Float16* sH2Hi  = (_Float16*)(smem + S_H2HI);
    _Float16* sH2Lo  = (_Float16*)(smem + S_H2LO);
    float*    sRaw   = (float*)smem;               // overlay (phase 3)

    const int tid  = threadIdx.x;
    const int lane = tid & 63;
    const int wave = tid >> 6;
    const int row0 = blockIdx.x * ROWS_PER_BLOCK;

    // ---- stage masked input directly into fragment layout -----------------
    if (tid < 512) {
        const int slot = tid;              // (mt, ks, lane)
        const int mt = slot >> 8;
        const int ks = (slot >> 6) & 3;
        const int l  = slot & 63;
        const int row = mt * 16 + (l & 15);
        const int c0  = ks * 32 + ((l >> 4) << 3);
        const int g   = row0 + row;
        float v[8];
        if (c0 < 64) {
            #pragma unroll
            for (int e = 0; e < 8; ++e)
                v[e] = ((c0 + e) & 1) ? 0.f : xp[g * 64 + c0 + e];
        } else {
            #pragma unroll
            for (int e = 0; e < 8; ++e)
                v[e] = ctxp[g * 64 + c0 - 64 + e];
        }
        v8h hi8, lo8;
        #pragma unroll
        for (int e = 0; e < 8; ++e) {
            _Float16 h, lo;
            split2(v[e], h, lo);
            hi8[e] = h; lo8[e] = lo;
        }
        *(v8h*)(sInpHi + slot * 8) = hi8;
        *(v8h*)(sInpLo + slot * 8) = lo8;
    }
    __syncthreads();

    gemm12<4>(sInpHi, sInpLo, W1Thi, W1Tlo, b1, sH1Hi, sH1Lo, wave, lane);
    __syncthreads();
    gemm12<16>(sH1Hi, sH1Lo, W2Thi, W2Tlo, b2, sH2Hi, sH2Lo, wave, lane);
    __syncthreads();

    // ---- GEMM3 + spline, 4 chunks of 8 transforms (24 tile-aligned tiles) --
    const float TB = 5.0f;
    float ldacc = 0.f;
    const int r  = (tid < 256) ? (tid >> 3) : 0;
    const int tl = tid & 7;
    const int t0s[4] = {0, 23, 47, 70};

    #pragma unroll 1
    for (int ch = 0; ch < 4; ++ch) {
        gemm3(sH2Hi, sH2Lo, W3Thi, W3Tlo, b3, sRaw, t0s[ch], wave, lane);
        __syncthreads();

        if (tid < 256) {
            const int t = ch * 8 + tl;
            const int g = row0 + r;
            const float* pr = sRaw + r * RAW_STRIDE + ((ch & 1) ? 8 : 0) + tl * 47;

            float mw = -1e30f, mh = -1e30f;
            #pragma unroll
            for (int i = 0; i < 16; ++i) {
                mw = fmaxf(mw, pr[i]);
                mh = fmaxf(mh, pr[16 + i]);
            }
            float wv[16], hv[16];
            float sw = 0.f, sh = 0.f;
            #pragma unroll
            for (int i = 0; i < 16; ++i) {
                wv[i] = __expf(pr[i] - mw);       sw += wv[i];
                hv[i] = __expf(pr[16 + i] - mh);  sh += hv[i];
            }
            const float scw = 10.f / sw;
            const float sch = 10.f / sh;

            const float xt = xp[g * 64 + 2 * t + 1];
            const float xc = fminf(fmaxf(xt, -TB + 1e-6f), TB - 1e-6f);

            float cum = -TB; int cnt = 0;
            #pragma unroll
            for (int i = 0; i < 16; ++i) {
                cum += wv[i] * scw;
                cnt += (cum < xc) ? 1 : 0;
            }
            const int bin = cnt > 15 ? 15 : cnt;

            float w_k = 0.f, cw_k = 0.f, h_k = 0.f, ch_k = 0.f;
            float cw = -TB, chh = -TB;
            #pragma unroll
            for (int i = 0; i < 16; ++i) {
                const float wi = wv[i] * scw;
                const float hi = hv[i] * sch;
                if (i == bin) { w_k = wi; cw_k = cw; h_k = hi; ch_k = chh; }
                cw += wi; chh += hi;
            }

            const float d_k  = (bin == 0)  ? 1.f : softplus_f(pr[31 + bin]);
            const float d_k1 = (bin == 15) ? 1.f : softplus_f(pr[32 + bin]);

            float xi = (xc - cw_k) / w_k;
            xi = fminf(fmaxf(xi, 0.f), 1.f);
            const float om = 1.f - xi;
            const float num = h_k * (d_k * xi * xi + 2.f * xi * om);
            const float den = d_k + (d_k1 + d_k - 2.f) * xi * om;
            const float yv  = ch_k + num / (den + 1e-8f);
            const float dv  = h_k * h_k * (d_k1 * xi * xi + 2.f * xi * om + d_k * om * om)
                              / (den * den * w_k + 1e-8f) + 1e-8f;

            float v = __logf(dv);
            v += __shfl_xor(v, 1);
            v += __shfl_xor(v, 2);
            v += __shfl_xor(v, 4);
            ldacc += v;

            outY[g * 64 + 2 * t]     = xp[g * 64 + 2 * t];
            outY[g * 64 + 2 * t + 1] = yv;
        }
        __syncthreads();
    }

    if (tid < 256 && tl == 0) outLD[row0 + r] = ldacc;
}

extern "C" void kernel_launch(void* const* d_in, const int* in_sizes, int n_in,
                              void* d_out, int out_size, void* d_ws, size_t ws_size,
                              hipStream_t stream) {
    (void)in_sizes; (void)n_in; (void)out_size; (void)ws_size;
    const float* x   = (const float*)d_in[0];
    const float* ctx = (const float*)d_in[1];
    const float* W1  = (const float*)d_in[2];
    const float* b1  = (const float*)d_in[3];
    const float* W2  = (const float*)d_in[4];
    const float* b2  = (const float*)d_in[5];
    const float* W3  = (const float*)d_in[6];
    const float* b3  = (const float*)d_in[7];

    _Float16* base = (_Float16*)d_ws;
    _Float16* W1Thi = base;                    // 512x128   = 65536
    _Float16* W1Tlo = base + 65536;
    _Float16* W2Thi = base + 131072;           // 512x512   = 262144
    _Float16* W2Tlo = base + 393216;
    _Float16* W3Thi = base + 655360;           // 1504x512  = 770048
    _Float16* W3Tlo = base + 1425408;

    nscl_prep_frag<<<(512 * 128 + 255) / 256, 256, 0, stream>>>(W1, W1Thi, W1Tlo, 128, 512);
    nscl_prep_frag<<<(512 * 512 + 255) / 256, 256, 0, stream>>>(W2, W2Thi, W2Tlo, 512, 512);
    nscl_prep_frag<<<(512 * 1504 + 255) / 256, 256, 0, stream>>>(W3, W3Thi, W3Tlo, 512, 1504);

    float* outY  = (float*)d_out;
    float* outLD = outY + 65536 * 64;

    nscl_fused<<<NBLOCKS, 1024, 0, stream>>>(x, ctx, b1, b2, b3,
                                             W1Thi, W1Tlo, W2Thi, W2Tlo, W3Thi, W3Tlo,
                                             outY, outLD);
}